// Round 17
// baseline (786.950 us; speedup 1.0000x reference)
//
#include <hip/hip_runtime.h>

#define NB_ 16
#define TQ_ 2048
#define TS_ 2048
#define DH_ 1024
#define QB_ 32
#define SB_ 256
#define NT_ 512

typedef _Float16 f16x8 __attribute__((ext_vector_type(8)));
typedef _Float16 f16x4 __attribute__((ext_vector_type(4)));
typedef float f32x4 __attribute__((ext_vector_type(4)));

// LDS-domain barrier: does NOT drain vmcnt; in-flight global(+lds) loads survive.
#define LDS_BARRIER() asm volatile("s_waitcnt lgkmcnt(0)\n\ts_barrier" ::: "memory")

__device__ inline uint32_t pack_h2(float a, float b) {
  union { _Float16 h[2]; uint32_t u; } c;
  c.h[0] = (_Float16)a; c.h[1] = (_Float16)b;
  return c.u;
}

__global__ void convert_f32_f16(const float* __restrict__ src, _Float16* __restrict__ dst) {
  size_t i = ((size_t)blockIdx.x * blockDim.x + threadIdx.x) * 8;
  float4 v0 = *(const float4*)(src + i);
  float4 v1 = *(const float4*)(src + i + 4);
  f16x8 o;
  o[0] = (_Float16)v0.x; o[1] = (_Float16)v0.y; o[2] = (_Float16)v0.z; o[3] = (_Float16)v0.w;
  o[4] = (_Float16)v1.x; o[5] = (_Float16)v1.y; o[6] = (_Float16)v1.z; o[7] = (_Float16)v1.w;
  *(f16x8*)(dst + i) = o;
}

__device__ inline f16x8 cvt8(const float* __restrict__ fp) {
  float4 a = *(const float4*)fp;
  float4 b = *(const float4*)(fp + 4);
  f16x8 t;
  t[0] = (_Float16)a.x; t[1] = (_Float16)a.y; t[2] = (_Float16)a.z; t[3] = (_Float16)a.w;
  t[4] = (_Float16)b.x; t[5] = (_Float16)b.y; t[6] = (_Float16)b.z; t[7] = (_Float16)b.w;
  return t;
}

template<bool WS16>
__device__ inline f16x8 ld8(const _Float16* __restrict__ hp, const float* __restrict__ fp, size_t idx) {
  if constexpr (WS16) return *(const f16x8*)(hp + idx);
  else return cvt8(fp + idx);
}

// global -> LDS direct staging, 16 B/lane; dest = wave-uniform base + lane*16.
typedef __attribute__((address_space(1))) const void g1void;
typedef __attribute__((address_space(3))) void l3void;
__device__ inline void gload_lds16(const void* g, void* l) {
  __builtin_amdgcn_global_load_lds((g1void*)g, (l3void*)l, 16, 0, 0);
}
__device__ inline uint32_t lds_off(void* p) {
  return (uint32_t)(size_t)(__attribute__((address_space(3))) char*)p;
}
__device__ inline f16x4 tr_read(uint32_t addr) {
  f16x4 d;
  asm volatile("ds_read_b64_tr_b16 %0, %1" : "=v"(d) : "v"(addr));
  return d;
}
__device__ inline f16x4 tr_read_o128(uint32_t addr) {
  f16x4 d;
  asm volatile("ds_read_b64_tr_b16 %0, %1 offset:128" : "=v"(d) : "v"(addr));
  return d;
}

// LDS layout (bytes), total 148352 (1 WG/CU):
//   q_base : 0      .. 65536   Q [32 q][1024 d] f16, byte=(q*2048+d*2)^((q&7)<<4)  [v12-verified]
//   s_lds  : 65536  .. 98816   S f32 [32 q][260]                                   [v12-verified]
//   p_base : 98816  .. 115200  P [32 q][256 s] f16, byte=(q*512+s*2)^((q&7)<<4)    [v12-verified]
//   vt_all : 115200 .. 147968  8 x 4096 per-wave V buffers (2 x 2048 double-buffer)
//            buffer = [2 n-groups][32 s][16 h] f16 row-major (gl_lds linear dest)
//   m/l/c  : 147968 .. 148352  softmax state
template<bool WS16>
__global__ __launch_bounds__(NT_, 2)
void attn_v17(const float* __restrict__ hid,
              const float* __restrict__ enc,
              const _Float16* __restrict__ encH,
              float* __restrict__ out) {
  __shared__ __attribute__((aligned(16))) char smem[148352];
  char*  const q_base = smem;
  float* const s_lds  = (float*)(smem + 65536);
  char*  const p_base = smem + 98816;
  char*  const vt_all = smem + 115200;
  float* const m_lds  = (float*)(smem + 147968);
  float* const l_lds  = m_lds + 32;
  float* const c_lds  = m_lds + 64;

  const int tid  = threadIdx.x;
  const int lane = tid & 63;
  const int wid  = tid >> 6;
  const int arow = lane & 15;
  const int agrp = lane >> 4;

  // XCD-affine: XCD x sweeps all 64 q-tiles of batch x, then batch x+8.
  const int bi  = blockIdx.x;
  const int x   = bi & 7;
  const int idx = bi >> 3;
  const int b   = x + 8 * (idx >> 6);
  const int q0  = (idx & 63) * QB_;

  const int hw = wid;  // PV h-chunk (128 wide); QK^T s-chunk = wid*32

  if (tid < 32) { m_lds[tid] = -__builtin_inff(); l_lds[tid] = 0.0f; }

  // ---- stage Q (32 x 1024) fp32 -> f16 into LDS, swizzled (v12-verified) ----
  {
    const float* qsrc = hid + ((size_t)b * TQ_ + q0) * DH_;
    #pragma unroll
    for (int k = 0; k < 16; ++k) {
      int i = tid + k * NT_;
      int q = i >> 8;
      int h = (i & 255) * 4;
      float4 v = *(const float4*)(qsrc + (size_t)q * DH_ + h);
      int byte = (q * 2048 + h * 2) ^ ((q & 7) << 4);
      *(uint32_t*)(q_base + byte)     = pack_h2(v.x, v.y);
      *(uint32_t*)(q_base + byte + 4) = pack_h2(v.z, v.w);
    }
  }
  __syncthreads();

  f32x4 o_acc[2][8];   // [m][hh*2+n] over 128 h  (64 AGPR persistent)
  #pragma unroll
  for (int m = 0; m < 2; ++m)
    #pragma unroll
    for (int n = 0; n < 8; ++n)
      o_acc[m][n] = {};

  char* const vtb = vt_all + wid * 4096;   // 2 x 2048 B double buffer
  const size_t enc_b = (size_t)b * TS_ * DH_;

  for (int st = 0; st < TS_ / SB_; ++st) {
    const int s0 = st * SB_;

    // issue V stage for pass p into buffer buf: [32 s][32 h] as 2 x [32][16] groups
    auto issueV = [&](int pass, int buf) {
      const int sp = pass >> 2, hh = pass & 3;
      const _Float16* g0 = encH + enc_b + (size_t)(s0 + sp * 32 + (lane >> 1)) * DH_
                           + hw * 128 + hh * 32 + (lane & 1) * 8;
      gload_lds16(g0,      vtb + buf * 2048);
      gload_lds16(g0 + 16, vtb + buf * 2048 + 1024);
    };

    // ================= QK^T (v12-verified): full-d S[32q][32s], s-chunk = wid*32 =================
    f32x4 sacc[2][2] = {{{}, {}}, {{}, {}}};
    {
      const size_t krow = enc_b + (size_t)(s0 + wid * 32 + arow) * DH_;
      #pragma unroll
      for (int kf = 0; kf < 32; ++kf) {
        const int d = kf * 32 + agrp * 8;
        f16x8 bf0 = ld8<WS16>(encH, enc, krow + d);
        f16x8 bf1 = ld8<WS16>(encH, enc, krow + (size_t)16 * DH_ + d);
        f16x8 af0 = *(const f16x8*)(q_base + ((arow * 2048 + d * 2) ^ ((arow & 7) << 4)));
        f16x8 af1 = *(const f16x8*)(q_base + (((16 + arow) * 2048 + d * 2) ^ ((arow & 7) << 4)));
        sacc[0][0] = __builtin_amdgcn_mfma_f32_16x16x32_f16(af0, bf0, sacc[0][0], 0, 0, 0);
        sacc[0][1] = __builtin_amdgcn_mfma_f32_16x16x32_f16(af0, bf1, sacc[0][1], 0, 0, 0);
        sacc[1][0] = __builtin_amdgcn_mfma_f32_16x16x32_f16(af1, bf0, sacc[1][0], 0, 0, 0);
        sacc[1][1] = __builtin_amdgcn_mfma_f32_16x16x32_f16(af1, bf1, sacc[1][1], 0, 0, 0);
      }
    }

    // ---- issue PV pass-0/1 V stages (fly across both LDS barriers) ----
    if constexpr (WS16) {
      issueV(0, 0);
      issueV(1, 1);
    }

    // write S tile (single writer per element)
    {
      const int sc = wid * 32 + arow;
      #pragma unroll
      for (int m = 0; m < 2; ++m)
        #pragma unroll
        for (int n = 0; n < 2; ++n)
          #pragma unroll
          for (int i2 = 0; i2 < 4; ++i2)
            s_lds[(m * 16 + agrp * 4 + i2) * 260 + sc + n * 16] = sacc[m][n][i2];
    }

    LDS_BARRIER();  // b1: S complete (V stages stay in flight)

    // ================= online softmax over [32 q][256 s] (v12-verified) =================
    {
      int q = tid >> 4, sq = tid & 15;
      const float* bp = s_lds + q * 260 + sq * 16;
      f32x4 v0 = *(const f32x4*)bp;
      f32x4 v1 = *(const f32x4*)(bp + 4);
      f32x4 v2 = *(const f32x4*)(bp + 8);
      f32x4 v3 = *(const f32x4*)(bp + 12);
      f32x4 vm = v0;
      #pragma unroll
      for (int j = 0; j < 4; ++j) { vm[j] = fmaxf(fmaxf(v0[j], v1[j]), fmaxf(v2[j], v3[j])); }
      float mx = fmaxf(fmaxf(vm[0], vm[1]), fmaxf(vm[2], vm[3]));
      #pragma unroll
      for (int o = 8; o; o >>= 1) mx = fmaxf(mx, __shfl_xor(mx, o));
      float mprev = m_lds[q];
      float mnew  = fmaxf(mprev, mx);
      float p[16], ps = 0.0f;
      #pragma unroll
      for (int j = 0; j < 4; ++j) {
        p[j]      = __expf(v0[j] - mnew);
        p[4 + j]  = __expf(v1[j] - mnew);
        p[8 + j]  = __expf(v2[j] - mnew);
        p[12 + j] = __expf(v3[j] - mnew);
      }
      #pragma unroll
      for (int j = 0; j < 16; ++j) ps += p[j];
      #pragma unroll
      for (int o = 8; o; o >>= 1) ps += __shfl_xor(ps, o);
      if (sq == 0) {
        float cf = __expf(mprev - mnew);
        m_lds[q] = mnew;
        l_lds[q] = l_lds[q] * cf + ps;
        c_lds[q] = cf;
      }
      #pragma unroll
      for (int g2 = 0; g2 < 2; ++g2) {
        f16x8 pw;
        #pragma unroll
        for (int j = 0; j < 8; ++j) pw[j] = (_Float16)p[g2 * 8 + j];
        *(f16x8*)(p_base + ((q * 512 + sq * 32 + g2 * 16) ^ ((q & 7) << 4))) = pw;
      }
    }

    LDS_BARRIER();  // b2: P + m/l/c complete

    // ---- rescale O ----
    #pragma unroll
    for (int m = 0; m < 2; ++m)
      #pragma unroll
      for (int i2 = 0; i2 < 4; ++i2) {
        float cf = c_lds[m * 16 + agrp * 4 + i2];
        #pragma unroll
        for (int n = 0; n < 8; ++n) o_acc[m][n][i2] *= cf;
      }

    // ================= PV =================
    if constexpr (WS16) {
      // 32 passes: sp = pass>>2 (32 s), hh = pass&3 (32 h); tr-read B-frags.
      f16x8 paf0 = {}, paf1 = {};
      #pragma unroll
      for (int pass = 0; pass < 32; ++pass) {
        const int sp = pass >> 2, hh = pass & 3;
        const int buf = pass & 1;
        if ((pass & 3) == 0) {
          paf0 = *(const f16x8*)(p_base +
              ((arow * 512 + sp * 64 + agrp * 16) ^ ((arow & 7) << 4)));
          paf1 = *(const f16x8*)(p_base +
              (((16 + arow) * 512 + sp * 64 + agrp * 16) ^ ((arow & 7) << 4)));
        }
        if (pass < 31) asm volatile("s_waitcnt vmcnt(2)" ::: "memory");
        else           asm volatile("s_waitcnt vmcnt(0)" ::: "memory");
        __builtin_amdgcn_sched_barrier(0);
        const uint32_t vb = lds_off(vtb + buf * 2048) + agrp * 256 + arow * 8;
        f16x4 b0lo = tr_read(vb);
        f16x4 b0hi = tr_read_o128(vb);
        f16x4 b1lo = tr_read(vb + 1024);
        f16x4 b1hi = tr_read_o128(vb + 1024);
        asm volatile("s_waitcnt lgkmcnt(0)" ::: "memory");
        __builtin_amdgcn_sched_barrier(0);
        if (pass < 30) issueV(pass + 2, buf);
        f16x8 bv0, bv1;
        #pragma unroll
        for (int j = 0; j < 4; ++j) {
          bv0[j] = b0lo[j]; bv0[4 + j] = b0hi[j];
          bv1[j] = b1lo[j]; bv1[4 + j] = b1hi[j];
        }
        __builtin_amdgcn_s_setprio(1);
        o_acc[0][hh * 2 + 0] = __builtin_amdgcn_mfma_f32_16x16x32_f16(paf0, bv0, o_acc[0][hh * 2 + 0], 0, 0, 0);
        o_acc[1][hh * 2 + 0] = __builtin_amdgcn_mfma_f32_16x16x32_f16(paf1, bv0, o_acc[1][hh * 2 + 0], 0, 0, 0);
        o_acc[0][hh * 2 + 1] = __builtin_amdgcn_mfma_f32_16x16x32_f16(paf0, bv1, o_acc[0][hh * 2 + 1], 0, 0, 0);
        o_acc[1][hh * 2 + 1] = __builtin_amdgcn_mfma_f32_16x16x32_f16(paf1, bv1, o_acc[1][hh * 2 + 1], 0, 0, 0);
        __builtin_amdgcn_s_setprio(0);
      }
    } else {
      // Fallback (correctness only): v12-style reg staging + transposed b32 writes.
      char* const vt = vtb;  // [64 h][32 s] stride 64 B
      const int c8 = (lane & 7) * 8;
      const int d2 = (lane >> 3) * 2;
      f16x8 stgA[2][2], stgB[2][2];
      #pragma unroll
      for (int it = 0; it < 2; ++it) {
        size_t base = enc_b + (size_t)(s0 + it * 16 + d2) * DH_ + hw * 128 + c8;
        stgA[it][0] = ld8<WS16>(encH, enc, base);
        stgA[it][1] = ld8<WS16>(encH, enc, base + DH_);
      }
      #pragma unroll
      for (int pass = 0; pass < 16; ++pass) {
        const int r = pass >> 3, sp = pass & 7;
        const bool useA = (pass & 1) == 0;
        #pragma unroll
        for (int it = 0; it < 2; ++it) {
          int sl = it * 16 + d2;
          #pragma unroll
          for (int jj = 0; jj < 8; ++jj) {
            int hl = c8 + jj;
            union { _Float16 h[2]; uint32_t u; } pk;
            pk.h[0] = useA ? stgA[it][0][jj] : stgB[it][0][jj];
            pk.h[1] = useA ? stgA[it][1][jj] : stgB[it][1][jj];
            *(uint32_t*)(vt + ((hl * 64 + sl * 2) ^ (((hl >> 3) & 7) << 4))) = pk.u;
          }
        }
        if (pass < 15) {
          const int rn = (pass + 1) >> 3, spn = (pass + 1) & 7;
          #pragma unroll
          for (int it = 0; it < 2; ++it) {
            size_t base = enc_b + (size_t)(s0 + spn * 32 + it * 16 + d2) * DH_
                          + hw * 128 + rn * 64 + c8;
            if (useA) { stgB[it][0] = ld8<WS16>(encH, enc, base); stgB[it][1] = ld8<WS16>(encH, enc, base + DH_); }
            else      { stgA[it][0] = ld8<WS16>(encH, enc, base); stgA[it][1] = ld8<WS16>(encH, enc, base + DH_); }
          }
        }
        f16x8 paf0 = *(const f16x8*)(p_base +
            ((arow * 512 + sp * 64 + agrp * 16) ^ ((arow & 7) << 4)));
        f16x8 paf1 = *(const f16x8*)(p_base +
            (((16 + arow) * 512 + sp * 64 + agrp * 16) ^ ((arow & 7) << 4)));
        #pragma unroll
        for (int n = 0; n < 4; ++n) {
          int hl = n * 16 + arow;
          f16x8 bv = *(const f16x8*)(vt + ((hl * 64 + agrp * 16) ^ (((hl >> 3) & 7) << 4)));
          o_acc[0][r * 4 + n] = __builtin_amdgcn_mfma_f32_16x16x32_f16(paf0, bv, o_acc[0][r * 4 + n], 0, 0, 0);
          o_acc[1][r * 4 + n] = __builtin_amdgcn_mfma_f32_16x16x32_f16(paf1, bv, o_acc[1][r * 4 + n], 0, 0, 0);
        }
      }
    }
  }

  // ================= epilogue: O / l =================
  #pragma unroll
  for (int m = 0; m < 2; ++m) {
    #pragma unroll
    for (int i2 = 0; i2 < 4; ++i2) {
      int qr = m * 16 + agrp * 4 + i2;
      float inv = 1.0f / l_lds[qr];
      #pragma unroll
      for (int n = 0; n < 8; ++n) {
        out[((size_t)(b * TQ_ + q0 + qr)) * DH_ + hw * 128 + (n >> 1) * 32 + (n & 1) * 16 + arow] =
            o_acc[m][n][i2] * inv;
      }
    }
  }
}

extern "C" void kernel_launch(void* const* d_in, const int* in_sizes, int n_in,
                              void* d_out, int out_size, void* d_ws, size_t ws_size,
                              hipStream_t stream) {
  (void)in_sizes; (void)n_in; (void)out_size;
  const float* hid = (const float*)d_in[0];
  const float* enc = (const float*)d_in[1];
  float* out = (float*)d_out;

  const size_t encN = (size_t)NB_ * TS_ * DH_;
  const bool ws16 = (ws_size >= encN * sizeof(_Float16));

  dim3 grid(NB_ * (TQ_ / QB_), 1, 1);
  dim3 block(NT_, 1, 1);

  if (ws16) {
    _Float16* encH = (_Float16*)d_ws;
    convert_f32_f16<<<dim3((unsigned)(encN / 8 / 256)), dim3(256), 0, stream>>>(enc, encH);
    attn_v17<true><<<grid, block, 0, stream>>>(hid, enc, encH, out);
  } else {
    attn_v17<false><<<grid, block, 0, stream>>>(hid, enc, nullptr, out);
  }
}

// Round 18
// 731.945 us; speedup vs baseline: 1.0751x; 1.0751x over previous
//
#include <hip/hip_runtime.h>

#define NB_ 16
#define TQ_ 2048
#define TS_ 2048
#define DH_ 1024
#define QB_ 32
#define SB_ 256
#define NT_ 512

typedef _Float16 f16x8 __attribute__((ext_vector_type(8)));
typedef _Float16 f16x4 __attribute__((ext_vector_type(4)));
typedef float f32x4 __attribute__((ext_vector_type(4)));
typedef uint32_t u32x2 __attribute__((ext_vector_type(2)));

// LDS-domain barrier: does NOT drain vmcnt; in-flight global loads survive.
#define LDS_BARRIER() asm volatile("s_waitcnt lgkmcnt(0)\n\ts_barrier" ::: "memory")

__device__ inline uint32_t pack_h2(float a, float b) {
  union { _Float16 h[2]; uint32_t u; } c;
  c.h[0] = (_Float16)a; c.h[1] = (_Float16)b;
  return c.u;
}
__device__ inline uint32_t pack_ff(_Float16 a, _Float16 b) {
  union { _Float16 h[2]; uint32_t u; } c;
  c.h[0] = a; c.h[1] = b;
  return c.u;
}

__global__ void convert_f32_f16(const float* __restrict__ src, _Float16* __restrict__ dst) {
  size_t i = ((size_t)blockIdx.x * blockDim.x + threadIdx.x) * 8;
  float4 v0 = *(const float4*)(src + i);
  float4 v1 = *(const float4*)(src + i + 4);
  f16x8 o;
  o[0] = (_Float16)v0.x; o[1] = (_Float16)v0.y; o[2] = (_Float16)v0.z; o[3] = (_Float16)v0.w;
  o[4] = (_Float16)v1.x; o[5] = (_Float16)v1.y; o[6] = (_Float16)v1.z; o[7] = (_Float16)v1.w;
  *(f16x8*)(dst + i) = o;
}

__device__ inline f16x8 cvt8(const float* __restrict__ fp) {
  float4 a = *(const float4*)fp;
  float4 b = *(const float4*)(fp + 4);
  f16x8 t;
  t[0] = (_Float16)a.x; t[1] = (_Float16)a.y; t[2] = (_Float16)a.z; t[3] = (_Float16)a.w;
  t[4] = (_Float16)b.x; t[5] = (_Float16)b.y; t[6] = (_Float16)b.z; t[7] = (_Float16)b.w;
  return t;
}

template<bool WS16>
__device__ inline f16x8 ld8(const _Float16* __restrict__ hp, const float* __restrict__ fp, size_t idx) {
  if constexpr (WS16) return *(const f16x8*)(hp + idx);
  else return cvt8(fp + idx);
}

// LDS layout (bytes), total 148352 (1 WG/CU) — identical to v12 (742 us verified):
//   q_base : 0      .. 65536   Q [32 q][1024 d] f16, byte=(q*2048+d*2)^((q&7)<<4)
//   s_lds  : 65536  .. 98816   S f32 [32 q][260]
//   p_base : 98816  .. 115200  P [32 q][256 s] f16, byte=(q*512+s*2)^((q&7)<<4)
//   vt_all : 115200 .. 147968  8 x 4096 per-wave V-transpose [64 h][32 s] stride 64
//            byte = (h*64 + s*2) ^ (((h>>3)&7)<<4)   (v12-verified aggregate)
//   m/l/c  : 147968 .. 148352  softmax state
template<bool WS16>
__global__ __launch_bounds__(NT_, 2)
void attn_v18(const float* __restrict__ hid,
              const float* __restrict__ enc,
              const _Float16* __restrict__ encH,
              float* __restrict__ out) {
  __shared__ __attribute__((aligned(16))) char smem[148352];
  char*  const q_base = smem;
  float* const s_lds  = (float*)(smem + 65536);
  char*  const p_base = smem + 98816;
  char*  const vt_all = smem + 115200;
  float* const m_lds  = (float*)(smem + 147968);
  float* const l_lds  = m_lds + 32;
  float* const c_lds  = m_lds + 64;

  const int tid  = threadIdx.x;
  const int lane = tid & 63;
  const int wid  = tid >> 6;
  const int arow = lane & 15;
  const int agrp = lane >> 4;

  // XCD-affine: XCD x sweeps all 64 q-tiles of batch x, then batch x+8.
  const int bi  = blockIdx.x;
  const int x   = bi & 7;
  const int idx = bi >> 3;
  const int b   = x + 8 * (idx >> 6);
  const int q0  = (idx & 63) * QB_;

  const int hw = wid;  // PV h-chunk (128 wide); QK^T s-chunk = wid*32

  if (tid < 32) { m_lds[tid] = -__builtin_inff(); l_lds[tid] = 0.0f; }

  // ---- stage Q (32 x 1024) fp32 -> f16 into LDS, swizzled (v12-verified) ----
  {
    const float* qsrc = hid + ((size_t)b * TQ_ + q0) * DH_;
    #pragma unroll
    for (int k = 0; k < 16; ++k) {
      int i = tid + k * NT_;
      int q = i >> 8;
      int h = (i & 255) * 4;
      float4 v = *(const float4*)(qsrc + (size_t)q * DH_ + h);
      int byte = (q * 2048 + h * 2) ^ ((q & 7) << 4);
      *(uint32_t*)(q_base + byte)     = pack_h2(v.x, v.y);
      *(uint32_t*)(q_base + byte + 4) = pack_h2(v.z, v.w);
    }
  }
  __syncthreads();

  f32x4 o_acc[2][8];   // [m][r*4+n] over 128 h  (64 AGPR persistent)
  #pragma unroll
  for (int m = 0; m < 2; ++m)
    #pragma unroll
    for (int n = 0; n < 8; ++n)
      o_acc[m][n] = {};

  char* const vt = vt_all + wid * 4096;
  const size_t enc_b = (size_t)b * TS_ * DH_;
  const int h8 = (lane & 7) * 8;        // V staging h-octet (within 64-h round)
  const int s4 = (lane >> 3) * 4;       // V staging s-quad base (0..28)

  // ring-2 staging, 4 f16x8 per slot (32 VGPR total, same as v12)
  f16x8 stg[2][4];

  for (int st = 0; st < TS_ / SB_; ++st) {
    const int s0 = st * SB_;

    auto loadV = [&](int pass, int slot) {
      const int r = pass >> 3, sp = pass & 7;
      size_t base = enc_b + (size_t)(s0 + sp * 32 + s4) * DH_ + hw * 128 + r * 64 + h8;
      stg[slot][0] = ld8<WS16>(encH, enc, base);
      stg[slot][1] = ld8<WS16>(encH, enc, base + DH_);
      stg[slot][2] = ld8<WS16>(encH, enc, base + 2 * DH_);
      stg[slot][3] = ld8<WS16>(encH, enc, base + 3 * DH_);
    };

    // ================= QK^T (v12-verified): full-d S[32q][32s], s-chunk = wid*32 =================
    f32x4 sacc[2][2] = {{{}, {}}, {{}, {}}};
    {
      const size_t krow = enc_b + (size_t)(s0 + wid * 32 + arow) * DH_;
      #pragma unroll
      for (int kf = 0; kf < 32; ++kf) {
        const int d = kf * 32 + agrp * 8;
        f16x8 bf0 = ld8<WS16>(encH, enc, krow + d);
        f16x8 bf1 = ld8<WS16>(encH, enc, krow + (size_t)16 * DH_ + d);
        f16x8 af0 = *(const f16x8*)(q_base + ((arow * 2048 + d * 2) ^ ((arow & 7) << 4)));
        f16x8 af1 = *(const f16x8*)(q_base + (((16 + arow) * 2048 + d * 2) ^ ((arow & 7) << 4)));
        sacc[0][0] = __builtin_amdgcn_mfma_f32_16x16x32_f16(af0, bf0, sacc[0][0], 0, 0, 0);
        sacc[0][1] = __builtin_amdgcn_mfma_f32_16x16x32_f16(af0, bf1, sacc[0][1], 0, 0, 0);
        sacc[1][0] = __builtin_amdgcn_mfma_f32_16x16x32_f16(af1, bf0, sacc[1][0], 0, 0, 0);
        sacc[1][1] = __builtin_amdgcn_mfma_f32_16x16x32_f16(af1, bf1, sacc[1][1], 0, 0, 0);
      }
    }

    // ---- issue PV pass-0 AND pass-1 V loads (fly across both LDS barriers) ----
    loadV(0, 0);
    loadV(1, 1);

    // write S tile (single writer per element)
    {
      const int sc = wid * 32 + arow;
      #pragma unroll
      for (int m = 0; m < 2; ++m)
        #pragma unroll
        for (int n = 0; n < 2; ++n)
          #pragma unroll
          for (int i2 = 0; i2 < 4; ++i2)
            s_lds[(m * 16 + agrp * 4 + i2) * 260 + sc + n * 16] = sacc[m][n][i2];
    }

    LDS_BARRIER();  // b1: S complete (V loads stay in flight)

    // ================= online softmax over [32 q][256 s] (v12-verified) =================
    {
      int q = tid >> 4, sq = tid & 15;
      const float* bp = s_lds + q * 260 + sq * 16;
      f32x4 v0 = *(const f32x4*)bp;
      f32x4 v1 = *(const f32x4*)(bp + 4);
      f32x4 v2 = *(const f32x4*)(bp + 8);
      f32x4 v3 = *(const f32x4*)(bp + 12);
      f32x4 vm = v0;
      #pragma unroll
      for (int j = 0; j < 4; ++j) { vm[j] = fmaxf(fmaxf(v0[j], v1[j]), fmaxf(v2[j], v3[j])); }
      float mx = fmaxf(fmaxf(vm[0], vm[1]), fmaxf(vm[2], vm[3]));
      #pragma unroll
      for (int o = 8; o; o >>= 1) mx = fmaxf(mx, __shfl_xor(mx, o));
      float mprev = m_lds[q];
      float mnew  = fmaxf(mprev, mx);
      float p[16], ps = 0.0f;
      #pragma unroll
      for (int j = 0; j < 4; ++j) {
        p[j]      = __expf(v0[j] - mnew);
        p[4 + j]  = __expf(v1[j] - mnew);
        p[8 + j]  = __expf(v2[j] - mnew);
        p[12 + j] = __expf(v3[j] - mnew);
      }
      #pragma unroll
      for (int j = 0; j < 16; ++j) ps += p[j];
      #pragma unroll
      for (int o = 8; o; o >>= 1) ps += __shfl_xor(ps, o);
      if (sq == 0) {
        float cf = __expf(mprev - mnew);
        m_lds[q] = mnew;
        l_lds[q] = l_lds[q] * cf + ps;
        c_lds[q] = cf;
      }
      #pragma unroll
      for (int g = 0; g < 4; ++g) {
        f16x4 pw;
        pw[0] = (_Float16)p[g * 4 + 0]; pw[1] = (_Float16)p[g * 4 + 1];
        pw[2] = (_Float16)p[g * 4 + 2]; pw[3] = (_Float16)p[g * 4 + 3];
        *(f16x4*)(p_base + ((q * 512 + sq * 32 + g * 8) ^ ((q & 7) << 4))) = pw;
      }
    }

    LDS_BARRIER();  // b2: P + m/l/c complete

    // ---- rescale O ----
    #pragma unroll
    for (int m = 0; m < 2; ++m)
      #pragma unroll
      for (int i2 = 0; i2 < 4; ++i2) {
        float cf = c_lds[m * 16 + agrp * 4 + i2];
        #pragma unroll
        for (int n = 0; n < 8; ++n) o_acc[m][n][i2] *= cf;
      }

    // ================= PV: 16 passes; same-slot reissue (prefetch distance = 2 passes) =================
    #pragma unroll
    for (int pass = 0; pass < 16; ++pass) {
      const int r    = pass >> 3, sp = pass & 7;
      const int slot = pass & 1;
      // 1. write Vt from stg[slot]: 8 x ds_write_b64 (merged; aggregate == v12 pattern)
      #pragma unroll
      for (int jj = 0; jj < 8; ++jj) {
        const int hl = h8 + jj;
        u32x2 w;
        w[0] = pack_ff(stg[slot][0][jj], stg[slot][1][jj]);
        w[1] = pack_ff(stg[slot][2][jj], stg[slot][3][jj]);
        *(u32x2*)(vt + ((hl * 64 + s4 * 2) ^ (((hl >> 3) & 7) << 4))) = w;
      }
      // 2. reissue this slot for pass+2 (lands ~2 passes later)
      if (pass < 14) loadV(pass + 2, slot);
      // 3. P A-frags for this s-phase
      f16x8 paf0 = *(const f16x8*)(p_base +
          ((arow * 512 + sp * 64 + agrp * 16) ^ ((arow & 7) << 4)));
      f16x8 paf1 = *(const f16x8*)(p_base +
          (((16 + arow) * 512 + sp * 64 + agrp * 16) ^ ((arow & 7) << 4)));
      // 4. Vt b128 reads + MFMA
      __builtin_amdgcn_s_setprio(1);
      #pragma unroll
      for (int n = 0; n < 4; ++n) {
        const int hl = n * 16 + arow;
        f16x8 bv = *(const f16x8*)(vt + ((hl * 64 + agrp * 16) ^ (((hl >> 3) & 7) << 4)));
        o_acc[0][r * 4 + n] = __builtin_amdgcn_mfma_f32_16x16x32_f16(paf0, bv, o_acc[0][r * 4 + n], 0, 0, 0);
        o_acc[1][r * 4 + n] = __builtin_amdgcn_mfma_f32_16x16x32_f16(paf1, bv, o_acc[1][r * 4 + n], 0, 0, 0);
      }
      __builtin_amdgcn_s_setprio(0);
    }
  }

  // ================= epilogue: O / l =================
  #pragma unroll
  for (int m = 0; m < 2; ++m) {
    #pragma unroll
    for (int i2 = 0; i2 < 4; ++i2) {
      int qr = m * 16 + agrp * 4 + i2;
      float inv = 1.0f / l_lds[qr];
      #pragma unroll
      for (int n = 0; n < 8; ++n) {
        out[((size_t)(b * TQ_ + q0 + qr)) * DH_ + hw * 128 + (n >> 2) * 64 + (n & 3) * 16 + arow] =
            o_acc[m][n][i2] * inv;
      }
    }
  }
}

extern "C" void kernel_launch(void* const* d_in, const int* in_sizes, int n_in,
                              void* d_out, int out_size, void* d_ws, size_t ws_size,
                              hipStream_t stream) {
  (void)in_sizes; (void)n_in; (void)out_size;
  const float* hid = (const float*)d_in[0];
  const float* enc = (const float*)d_in[1];
  float* out = (float*)d_out;

  const size_t encN = (size_t)NB_ * TS_ * DH_;
  const bool ws16 = (ws_size >= encN * sizeof(_Float16));

  dim3 grid(NB_ * (TQ_ / QB_), 1, 1);
  dim3 block(NT_, 1, 1);

  if (ws16) {
    _Float16* encH = (_Float16*)d_ws;
    convert_f32_f16<<<dim3((unsigned)(encN / 8 / 256)), dim3(256), 0, stream>>>(enc, encH);
    attn_v18<true><<<grid, block, 0, stream>>>(hid, enc, encH, out);
  } else {
    attn_v18<false><<<grid, block, 0, stream>>>(hid, enc, nullptr, out);
  }
}

// Round 19
// 721.724 us; speedup vs baseline: 1.0904x; 1.0142x over previous
//
#include <hip/hip_runtime.h>

#define NB_ 16
#define TQ_ 2048
#define TS_ 2048
#define DH_ 1024
#define QB_ 32
#define SB_ 256
#define NT_ 512

typedef _Float16 f16x8 __attribute__((ext_vector_type(8)));
typedef _Float16 f16x4 __attribute__((ext_vector_type(4)));
typedef float f32x4 __attribute__((ext_vector_type(4)));
typedef float f32x16 __attribute__((ext_vector_type(16)));
typedef uint32_t u32x2 __attribute__((ext_vector_type(2)));

// LDS-domain barrier: does NOT drain vmcnt; in-flight global loads survive.
#define LDS_BARRIER() asm volatile("s_waitcnt lgkmcnt(0)\n\ts_barrier" ::: "memory")

__device__ inline uint32_t pack_h2(float a, float b) {
  union { _Float16 h[2]; uint32_t u; } c;
  c.h[0] = (_Float16)a; c.h[1] = (_Float16)b;
  return c.u;
}
__device__ inline uint32_t pack_ff(_Float16 a, _Float16 b) {
  union { _Float16 h[2]; uint32_t u; } c;
  c.h[0] = a; c.h[1] = b;
  return c.u;
}

__global__ void convert_f32_f16(const float* __restrict__ src, _Float16* __restrict__ dst) {
  size_t i = ((size_t)blockIdx.x * blockDim.x + threadIdx.x) * 8;
  float4 v0 = *(const float4*)(src + i);
  float4 v1 = *(const float4*)(src + i + 4);
  f16x8 o;
  o[0] = (_Float16)v0.x; o[1] = (_Float16)v0.y; o[2] = (_Float16)v0.z; o[3] = (_Float16)v0.w;
  o[4] = (_Float16)v1.x; o[5] = (_Float16)v1.y; o[6] = (_Float16)v1.z; o[7] = (_Float16)v1.w;
  *(f16x8*)(dst + i) = o;
}

__device__ inline f16x8 cvt8(const float* __restrict__ fp) {
  float4 a = *(const float4*)fp;
  float4 b = *(const float4*)(fp + 4);
  f16x8 t;
  t[0] = (_Float16)a.x; t[1] = (_Float16)a.y; t[2] = (_Float16)a.z; t[3] = (_Float16)a.w;
  t[4] = (_Float16)b.x; t[5] = (_Float16)b.y; t[6] = (_Float16)b.z; t[7] = (_Float16)b.w;
  return t;
}

template<bool WS16>
__device__ inline f16x8 ld8(const _Float16* __restrict__ hp, const float* __restrict__ fp, size_t idx) {
  if constexpr (WS16) return *(const f16x8*)(hp + idx);
  else return cvt8(fp + idx);
}

// LDS layout (bytes), total 148352 (1 WG/CU) — identical to v18 (732 us verified):
//   q_base : 0      .. 65536   Q [32 q][1024 d] f16, byte=(q*2048+d*2)^((q&7)<<4)
//   s_lds  : 65536  .. 98816   S f32 [32 q][260]
//   p_base : 98816  .. 115200  P [32 q][256 s] f16, byte=(q*512+s*2)^((q&7)<<4)
//   vt_all : 115200 .. 147968  8 x 4096 per-wave V-transpose [64 h][32 s] stride 64
//            byte = (h*64 + s*2) ^ (((h>>3)&7)<<4)
//   m/l/c  : 147968 .. 148352  softmax state
template<bool WS16>
__global__ __launch_bounds__(NT_, 2)
void attn_v19(const float* __restrict__ hid,
              const float* __restrict__ enc,
              const _Float16* __restrict__ encH,
              float* __restrict__ out) {
  __shared__ __attribute__((aligned(16))) char smem[148352];
  char*  const q_base = smem;
  float* const s_lds  = (float*)(smem + 65536);
  char*  const p_base = smem + 98816;
  char*  const vt_all = smem + 115200;
  float* const m_lds  = (float*)(smem + 147968);
  float* const l_lds  = m_lds + 32;
  float* const c_lds  = m_lds + 64;

  const int tid  = threadIdx.x;
  const int lane = tid & 63;
  const int wid  = tid >> 6;
  const int q5   = lane & 31;   // 32x32 MFMA row/col index
  const int kgrp = lane >> 5;   // 32x32 MFMA k-group (0/1), k-offset = kgrp*8

  // XCD-affine: XCD x sweeps all 64 q-tiles of batch x, then batch x+8.
  const int bi  = blockIdx.x;
  const int x   = bi & 7;
  const int idx = bi >> 3;
  const int b   = x + 8 * (idx >> 6);
  const int q0  = (idx & 63) * QB_;

  const int hw = wid;  // PV h-chunk (128 wide); QK^T s-chunk = wid*32

  if (tid < 32) { m_lds[tid] = -__builtin_inff(); l_lds[tid] = 0.0f; }

  // ---- stage Q (32 x 1024) fp32 -> f16 into LDS, swizzled (v12/v18-verified) ----
  {
    const float* qsrc = hid + ((size_t)b * TQ_ + q0) * DH_;
    #pragma unroll
    for (int k = 0; k < 16; ++k) {
      int i = tid + k * NT_;
      int q = i >> 8;
      int h = (i & 255) * 4;
      float4 v = *(const float4*)(qsrc + (size_t)q * DH_ + h);
      int byte = (q * 2048 + h * 2) ^ ((q & 7) << 4);
      *(uint32_t*)(q_base + byte)     = pack_h2(v.x, v.y);
      *(uint32_t*)(q_base + byte + 4) = pack_h2(v.z, v.w);
    }
  }
  __syncthreads();

  // O accumulator: 4 h-tiles of 32q x 32h (f32x16 each) = 64 AGPR persistent.
  // o_acc[t]: h = hw*128 + (t>>1)*64 + (t&1)*32 + q5; q = (reg&3)+8*(reg>>2)+4*kgrp
  f32x16 o_acc[4];
  #pragma unroll
  for (int t = 0; t < 4; ++t) o_acc[t] = {};

  char* const vt = vt_all + wid * 4096;
  const size_t enc_b = (size_t)b * TS_ * DH_;
  const int h8 = (lane & 7) * 8;        // V staging h-octet (within 64-h round)
  const int s4 = (lane >> 3) * 4;       // V staging s-quad base (0..28)

  // ring-2 staging, 4 f16x8 per slot (32 VGPR total) — v18-verified
  f16x8 stg[2][4];

  for (int st = 0; st < TS_ / SB_; ++st) {
    const int s0 = st * SB_;

    auto loadV = [&](int pass, int slot) {
      const int r = pass >> 3, sp = pass & 7;
      size_t base = enc_b + (size_t)(s0 + sp * 32 + s4) * DH_ + hw * 128 + r * 64 + h8;
      stg[slot][0] = ld8<WS16>(encH, enc, base);
      stg[slot][1] = ld8<WS16>(encH, enc, base + DH_);
      stg[slot][2] = ld8<WS16>(encH, enc, base + 2 * DH_);
      stg[slot][3] = ld8<WS16>(encH, enc, base + 3 * DH_);
    };

    // ================= QK^T: 32x32x16, S[32q][32s], 2 chains over even/odd k-steps =================
    f32x16 acc0 = {}, acc1 = {};
    {
      const size_t krow = enc_b + (size_t)(s0 + wid * 32 + q5) * DH_;
      #pragma unroll
      for (int kf = 0; kf < 32; ++kf) {
        const int d0 = kf * 32 + kgrp * 8;        // even k-step
        const int d1 = d0 + 16;                   // odd k-step
        f16x8 aq0 = *(const f16x8*)(q_base + ((q5 * 2048 + d0 * 2) ^ ((q5 & 7) << 4)));
        f16x8 bk0 = ld8<WS16>(encH, enc, krow + d0);
        acc0 = __builtin_amdgcn_mfma_f32_32x32x16_f16(aq0, bk0, acc0, 0, 0, 0);
        f16x8 aq1 = *(const f16x8*)(q_base + ((q5 * 2048 + d1 * 2) ^ ((q5 & 7) << 4)));
        f16x8 bk1 = ld8<WS16>(encH, enc, krow + d1);
        acc1 = __builtin_amdgcn_mfma_f32_32x32x16_f16(aq1, bk1, acc1, 0, 0, 0);
      }
    }

    // ---- issue PV pass-0 AND pass-1 V loads (fly across both LDS barriers) ----
    loadV(0, 0);
    loadV(1, 1);

    // write S tile: col = wid*32 + q5; row = (reg&3)+8*(reg>>2)+4*kgrp
    {
      f32x16 acc = acc0 + acc1;
      const int sc = wid * 32 + q5;
      #pragma unroll
      for (int reg = 0; reg < 16; ++reg) {
        const int qr = (reg & 3) + 8 * (reg >> 2) + 4 * kgrp;
        s_lds[qr * 260 + sc] = acc[reg];
      }
    }

    LDS_BARRIER();  // b1: S complete (V loads stay in flight)

    // ================= online softmax over [32 q][256 s] (v12-verified) =================
    {
      int q = tid >> 4, sq = tid & 15;
      const float* bp = s_lds + q * 260 + sq * 16;
      f32x4 v0 = *(const f32x4*)bp;
      f32x4 v1 = *(const f32x4*)(bp + 4);
      f32x4 v2 = *(const f32x4*)(bp + 8);
      f32x4 v3 = *(const f32x4*)(bp + 12);
      f32x4 vm = v0;
      #pragma unroll
      for (int j = 0; j < 4; ++j) { vm[j] = fmaxf(fmaxf(v0[j], v1[j]), fmaxf(v2[j], v3[j])); }
      float mx = fmaxf(fmaxf(vm[0], vm[1]), fmaxf(vm[2], vm[3]));
      #pragma unroll
      for (int o = 8; o; o >>= 1) mx = fmaxf(mx, __shfl_xor(mx, o));
      float mprev = m_lds[q];
      float mnew  = fmaxf(mprev, mx);
      float p[16], ps = 0.0f;
      #pragma unroll
      for (int j = 0; j < 4; ++j) {
        p[j]      = __expf(v0[j] - mnew);
        p[4 + j]  = __expf(v1[j] - mnew);
        p[8 + j]  = __expf(v2[j] - mnew);
        p[12 + j] = __expf(v3[j] - mnew);
      }
      #pragma unroll
      for (int j = 0; j < 16; ++j) ps += p[j];
      #pragma unroll
      for (int o = 8; o; o >>= 1) ps += __shfl_xor(ps, o);
      if (sq == 0) {
        float cf = __expf(mprev - mnew);
        m_lds[q] = mnew;
        l_lds[q] = l_lds[q] * cf + ps;
        c_lds[q] = cf;
      }
      #pragma unroll
      for (int g = 0; g < 4; ++g) {
        f16x4 pw;
        pw[0] = (_Float16)p[g * 4 + 0]; pw[1] = (_Float16)p[g * 4 + 1];
        pw[2] = (_Float16)p[g * 4 + 2]; pw[3] = (_Float16)p[g * 4 + 3];
        *(f16x4*)(p_base + ((q * 512 + sq * 32 + g * 8) ^ ((q & 7) << 4))) = pw;
      }
    }

    LDS_BARRIER();  // b2: P + m/l/c complete

    // ---- rescale O (per-reg q mapping) ----
    {
      float cf[16];
      #pragma unroll
      for (int reg = 0; reg < 16; ++reg)
        cf[reg] = c_lds[(reg & 3) + 8 * (reg >> 2) + 4 * kgrp];
      #pragma unroll
      for (int t = 0; t < 4; ++t)
        #pragma unroll
        for (int reg = 0; reg < 16; ++reg)
          o_acc[t][reg] *= cf[reg];
    }

    // ================= PV: 16 passes; 32x32x16; ring-2 same-slot reissue =================
    #pragma unroll
    for (int pass = 0; pass < 16; ++pass) {
      const int r    = pass >> 3, sp = pass & 7;
      const int slot = pass & 1;
      // 1. write Vt from stg[slot]: 8 x ds_write_b64 (v18-verified aggregate)
      #pragma unroll
      for (int jj = 0; jj < 8; ++jj) {
        const int hl = h8 + jj;
        u32x2 w;
        w[0] = pack_ff(stg[slot][0][jj], stg[slot][1][jj]);
        w[1] = pack_ff(stg[slot][2][jj], stg[slot][3][jj]);
        *(u32x2*)(vt + ((hl * 64 + s4 * 2) ^ (((hl >> 3) & 7) << 4))) = w;
      }
      // 2. reissue this slot for pass+2
      if (pass < 14) loadV(pass + 2, slot);
      // 3. P A-frags: ks = 2sp (s = sp*32 + kgrp*8) and 2sp+1 (s = sp*32 + 16 + kgrp*8)
      f16x8 pa0 = *(const f16x8*)(p_base +
          ((q5 * 512 + sp * 64 + kgrp * 16) ^ ((q5 & 7) << 4)));
      f16x8 pa1 = *(const f16x8*)(p_base +
          ((q5 * 512 + sp * 64 + 32 + kgrp * 16) ^ ((q5 & 7) << 4)));
      // 4. Vt B-frags + MFMA: 2 h-tiles x 2 k-steps
      __builtin_amdgcn_s_setprio(1);
      #pragma unroll
      for (int ht = 0; ht < 2; ++ht) {
        const int hl  = ht * 32 + q5;
        const int swz = ((hl >> 3) & 7) << 4;
        f16x8 bv0 = *(const f16x8*)(vt + ((hl * 64 + kgrp * 16) ^ swz));
        f16x8 bv1 = *(const f16x8*)(vt + ((hl * 64 + 32 + kgrp * 16) ^ swz));
        o_acc[r * 2 + ht] = __builtin_amdgcn_mfma_f32_32x32x16_f16(pa0, bv0, o_acc[r * 2 + ht], 0, 0, 0);
        o_acc[r * 2 + ht] = __builtin_amdgcn_mfma_f32_32x32x16_f16(pa1, bv1, o_acc[r * 2 + ht], 0, 0, 0);
      }
      __builtin_amdgcn_s_setprio(0);
    }
  }

  // ================= epilogue: O / l =================
  {
    float inv[16];
    #pragma unroll
    for (int reg = 0; reg < 16; ++reg)
      inv[reg] = 1.0f / l_lds[(reg & 3) + 8 * (reg >> 2) + 4 * kgrp];
    #pragma unroll
    for (int t = 0; t < 4; ++t) {
      const int hcol = hw * 128 + (t >> 1) * 64 + (t & 1) * 32 + q5;
      #pragma unroll
      for (int reg = 0; reg < 16; ++reg) {
        const int qr = (reg & 3) + 8 * (reg >> 2) + 4 * kgrp;
        out[((size_t)(b * TQ_ + q0 + qr)) * DH_ + hcol] = o_acc[t][reg] * inv[reg];
      }
    }
  }
}

extern "C" void kernel_launch(void* const* d_in, const int* in_sizes, int n_in,
                              void* d_out, int out_size, void* d_ws, size_t ws_size,
                              hipStream_t stream) {
  (void)in_sizes; (void)n_in; (void)out_size;
  const float* hid = (const float*)d_in[0];
  const float* enc = (const float*)d_in[1];
  float* out = (float*)d_out;

  const size_t encN = (size_t)NB_ * TS_ * DH_;
  const bool ws16 = (ws_size >= encN * sizeof(_Float16));

  dim3 grid(NB_ * (TQ_ / QB_), 1, 1);
  dim3 block(NT_, 1, 1);

  if (ws16) {
    _Float16* encH = (_Float16*)d_ws;
    convert_f32_f16<<<dim3((unsigned)(encN / 8 / 256)), dim3(256), 0, stream>>>(enc, encH);
    attn_v19<true><<<grid, block, 0, stream>>>(hid, enc, encH, out);
  } else {
    attn_v19<false><<<grid, block, 0, stream>>>(hid, enc, nullptr, out);
  }
}